// Round 1
// baseline (678.344 us; speedup 1.0000x reference)
//
#include <hip/hip_runtime.h>
#include <hip/hip_bf16.h>

#define D_IN 384
#define D_H  64

typedef __attribute__((ext_vector_type(8))) short short8;
typedef __attribute__((ext_vector_type(4))) float f32x4;

__device__ __forceinline__ unsigned short f2bf(float f){
  unsigned u = __float_as_uint(f);
  u += 0x7fffu + ((u >> 16) & 1u);   // round-to-nearest-even
  return (unsigned short)(u >> 16);
}

// ---- K1: init counters ----
__global__ void k_init(int* cnt, int* cursor, int* gctr, int N){
  int i = blockIdx.x * blockDim.x + threadIdx.x;
  if (i < N){ cnt[i] = 0; cursor[i] = 0; }
  if (i == 0) *gctr = 0;
}

// ---- K2: in-degree count over real edges (dst = ei[E+e]) ----
__global__ void k_count(const int* __restrict__ ei, int* cnt, int E){
  int e = blockIdx.x * blockDim.x + threadIdx.x;
  if (e < E) atomicAdd(&cnt[ei[E + e]], 1);
}

// ---- K3: allocate CSR rows (block scan + single global atomic), dis = rsqrt(deg+1) ----
__global__ void k_alloc(const int* __restrict__ cnt, int* rowstart, float* dis,
                        int* gctr, int N){
  __shared__ int sd[256];
  __shared__ int sbase;
  int t = threadIdx.x;
  int i = blockIdx.x * 256 + t;
  int c = (i < N) ? cnt[i] : 0;
  sd[t] = c; __syncthreads();
  for (int off = 1; off < 256; off <<= 1){
    int v = (t >= off) ? sd[t - off] : 0;
    __syncthreads();
    sd[t] += v;
    __syncthreads();
  }
  int incl = sd[t];
  if (t == 255) sbase = atomicAdd(gctr, incl);
  __syncthreads();
  if (i < N){
    rowstart[i] = sbase + (incl - c);
    dis[i] = rsqrtf((float)(c + 1));   // +1 for the self-loop; deg always > 0
  }
}

// ---- K4: scatter src indices into CSR slots ----
__global__ void k_fill(const int* __restrict__ ei, const int* __restrict__ rowstart,
                       int* cursor, int* csr, int E){
  int e = blockIdx.x * blockDim.x + threadIdx.x;
  if (e < E){
    int s = ei[e];
    int d = ei[E + e];
    int pos = atomicAdd(&cursor[d], 1);
    csr[rowstart[d] + pos] = s;
  }
}

// ---- K5: h = x @ W_gcn, bf16 MFMA 16x16x32, fp32 accum ----
// Block tile: 64 nodes x 64 features, K chunked by 128.
// LDS holds A/B in fragment order: [tile][kstep][lane][j] so ds_read_b128 is
// perfectly lane-sequential (conflict-free).
__global__ __launch_bounds__(256) void k_gemm(const float* __restrict__ x,
                                              const float* __restrict__ W,
                                              float* __restrict__ h, int N){
  __shared__ __align__(16) short a_sw[4 * 4 * 64 * 8];  // 16 KiB
  __shared__ __align__(16) short b_sw[4 * 4 * 64 * 8];  // 16 KiB
  const int t = threadIdx.x;
  const int node0 = blockIdx.x * 64;
  const int w = t >> 6;     // wave id = m-tile
  const int l = t & 63;     // lane

  f32x4 acc[4];
  #pragma unroll
  for (int nt = 0; nt < 4; nt++) acc[nt] = (f32x4){0.f, 0.f, 0.f, 0.f};

  for (int c = 0; c < 3; c++){
    const int kbase = c * 128;
    // stage: each thread fills 4 A-cells and 4 B-cells (16 B each)
    #pragma unroll
    for (int r = 0; r < 4; r++){
      int id  = t + 256 * r;        // 0..1023
      int cl  = id & 63;
      int s   = (id >> 6) & 3;      // k-step within chunk
      int tl  = id >> 8;            // m-tile (A) / n-tile (B)
      int k   = kbase + s * 32 + ((cl >> 4) << 3);  // quad*8
      // A cell: x[node0 + tl*16 + (cl&15)][k..k+7]
      {
        int m = tl * 16 + (cl & 15);
        int node = node0 + m;
        uint4 pv;
        if (node < N){
          const float* xp = &x[(size_t)node * D_IN + k];
          float4 u0 = *(const float4*)xp;
          float4 u1 = *(const float4*)(xp + 4);
          pv.x = (unsigned)f2bf(u0.x) | ((unsigned)f2bf(u0.y) << 16);
          pv.y = (unsigned)f2bf(u0.z) | ((unsigned)f2bf(u0.w) << 16);
          pv.z = (unsigned)f2bf(u1.x) | ((unsigned)f2bf(u1.y) << 16);
          pv.w = (unsigned)f2bf(u1.z) | ((unsigned)f2bf(u1.w) << 16);
        } else {
          pv.x = pv.y = pv.z = pv.w = 0u;
        }
        *reinterpret_cast<uint4*>(&a_sw[id * 8]) = pv;
      }
      // B cell: W[k..k+7][tl*16 + (cl&15)]  (stride 64 floats along k)
      {
        int n = tl * 16 + (cl & 15);
        const float* wp = &W[(size_t)k * D_H + n];
        uint4 qv;
        qv.x = (unsigned)f2bf(wp[0])   | ((unsigned)f2bf(wp[64])  << 16);
        qv.y = (unsigned)f2bf(wp[128]) | ((unsigned)f2bf(wp[192]) << 16);
        qv.z = (unsigned)f2bf(wp[256]) | ((unsigned)f2bf(wp[320]) << 16);
        qv.w = (unsigned)f2bf(wp[384]) | ((unsigned)f2bf(wp[448]) << 16);
        *reinterpret_cast<uint4*>(&b_sw[id * 8]) = qv;
      }
    }
    __syncthreads();
    #pragma unroll
    for (int s = 0; s < 4; s++){
      short8 a = *reinterpret_cast<const short8*>(&a_sw[((w * 4 + s) * 64 + l) * 8]);
      #pragma unroll
      for (int nt = 0; nt < 4; nt++){
        short8 b = *reinterpret_cast<const short8*>(&b_sw[((nt * 4 + s) * 64 + l) * 8]);
        acc[nt] = __builtin_amdgcn_mfma_f32_16x16x32_bf16(a, b, acc[nt], 0, 0, 0);
      }
    }
    __syncthreads();
  }
  // epilogue: C/D layout col = lane&15, row = (lane>>4)*4 + reg
  const int qd = l >> 4;
  const int col0 = l & 15;
  #pragma unroll
  for (int nt = 0; nt < 4; nt++){
    #pragma unroll
    for (int r = 0; r < 4; r++){
      int node = node0 + w * 16 + qd * 4 + r;
      if (node < N) h[(size_t)node * D_H + nt * 16 + col0] = acc[nt][r];
    }
  }
}

// ---- K6: per-node aggregation (wave per node, lane = feature), relu(agg + b) ----
__global__ void k_agg(const float* __restrict__ h, const int* __restrict__ csr,
                      const int* __restrict__ rowstart, const int* __restrict__ cnt,
                      const float* __restrict__ dis, const float* __restrict__ bg,
                      float* __restrict__ hout, int N){
  int gid = blockIdx.x * blockDim.x + threadIdx.x;
  int i = gid >> 6;
  int f = gid & 63;
  if (i >= N) return;
  float dii = dis[i];
  float acc = h[(size_t)i * D_H + f] * dii * dii;     // self-loop message
  int rs = rowstart[i];
  int re = rs + cnt[i];
  int e = rs;
  for (; e + 4 <= re; e += 4){
    int s0 = csr[e], s1 = csr[e + 1], s2 = csr[e + 2], s3 = csr[e + 3];
    float w0 = dis[s0] * dii, w1 = dis[s1] * dii, w2 = dis[s2] * dii, w3 = dis[s3] * dii;
    acc += h[(size_t)s0 * D_H + f] * w0;
    acc += h[(size_t)s1 * D_H + f] * w1;
    acc += h[(size_t)s2 * D_H + f] * w2;
    acc += h[(size_t)s3 * D_H + f] * w3;
  }
  for (; e < re; e++){
    int s = csr[e];
    acc += h[(size_t)s * D_H + f] * dis[s] * dii;
  }
  float v = acc + bg[f];
  hout[(size_t)i * D_H + f] = v > 0.f ? v : 0.f;
}

// ---- K7: pool (sorted batch -> binary search range) + classifier ----
__global__ void k_pool(const float* __restrict__ hout, const int* __restrict__ batch,
                       const float* __restrict__ wc, const float* __restrict__ bc,
                       float* __restrict__ out, int N, int G){
  int g = blockIdx.x;
  int t = threadIdx.x;
  int lo = 0, hi = N;
  while (lo < hi){ int m = (lo + hi) >> 1; if (batch[m] < g) lo = m + 1; else hi = m; }
  int start = lo;
  lo = start; hi = N;
  while (lo < hi){ int m = (lo + hi) >> 1; if (batch[m] < g + 1) lo = m + 1; else hi = m; }
  int end = lo;

  int f = t & 63;
  int r = t >> 6;
  float sum = 0.f;
  for (int i = start + r; i < end; i += 4) sum += hout[(size_t)i * D_H + f];
  __shared__ float red[256];
  red[t] = sum;
  __syncthreads();
  if (t < 64){
    float z = red[t] + red[t + 64] + red[t + 128] + red[t + 192];
    float p = z * wc[t];
    #pragma unroll
    for (int off = 32; off > 0; off >>= 1) p += __shfl_down(p, off);
    if (t == 0) out[g] = p + bc[0];
  }
}

extern "C" void kernel_launch(void* const* d_in, const int* in_sizes, int n_in,
                              void* d_out, int out_size, void* d_ws, size_t ws_size,
                              hipStream_t stream){
  const float* x     = (const float*)d_in[0];
  const int*   ei    = (const int*)d_in[1];    // [2,E] flat: [0..E)=src, [E..2E)=dst
  const int*   batch = (const int*)d_in[2];
  const float* Wg    = (const float*)d_in[3];
  const float* bg    = (const float*)d_in[4];
  const float* wc    = (const float*)d_in[5];
  const float* bc    = (const float*)d_in[6];
  float* out = (float*)d_out;

  const int N = in_sizes[2];
  const int E = in_sizes[1] / 2;
  const int G = out_size;

  char* ws = (char*)d_ws;
  size_t off = 0;
  auto alloc = [&](size_t bytes) -> void* {
    void* p = ws + off;
    off += (bytes + 255) & ~(size_t)255;
    return p;
  };
  int*   cnt      = (int*)  alloc((size_t)N * 4);
  int*   rowstart = (int*)  alloc((size_t)N * 4);
  int*   cursor   = (int*)  alloc((size_t)N * 4);
  float* dis      = (float*)alloc((size_t)N * 4);
  int*   gctr     = (int*)  alloc(256);
  int*   csr      = (int*)  alloc((size_t)E * 4);
  float* h        = (float*)alloc((size_t)N * D_H * 4);
  float* hout     = (float*)alloc((size_t)N * D_H * 4);

  k_init <<<(N + 255) / 256, 256, 0, stream>>>(cnt, cursor, gctr, N);
  k_count<<<(E + 255) / 256, 256, 0, stream>>>(ei, cnt, E);
  k_alloc<<<(N + 255) / 256, 256, 0, stream>>>(cnt, rowstart, dis, gctr, N);
  k_fill <<<(E + 255) / 256, 256, 0, stream>>>(ei, rowstart, cursor, csr, E);
  k_gemm <<<(N + 63) / 64, 256, 0, stream>>>(x, Wg, h, N);
  k_agg  <<<(N + 3) / 4, 256, 0, stream>>>(h, csr, rowstart, cnt, dis, bg, hout, N);
  k_pool <<<G, 256, 0, stream>>>(hout, batch, wc, bc, out, N, G);
}